// Round 3
// baseline (267.584 us; speedup 1.0000x reference)
//
#include <hip/hip_runtime.h>
#include <hip/hip_bf16.h>

#define NUM_HEADS 4
#define HEAD_DIM 64
#define HD 256
#define QD 256
#define VD 256
#define B_SZ 32
#define N_NODES 8192
#define NEG_SLOPE 0.2f

typedef short bf16x8 __attribute__((ext_vector_type(8)));
typedef unsigned short u16x8 __attribute__((ext_vector_type(8)));
typedef float f32x4 __attribute__((ext_vector_type(4)));

static __device__ __forceinline__ unsigned short f2bf(float f) {
    __hip_bfloat16 h = __float2bfloat16(f);
    return *reinterpret_cast<unsigned short*>(&h);
}

// ---------------------------------------------------------------------------
// Kernel 1: prep
//  blocks 0..31   : hqb[b][col] = query[b]@Wq[:,col] + 2*bq[col]
//  blocks 32..63  : pack Wq -> bf16 fragment order
// ---------------------------------------------------------------------------
__global__ __launch_bounds__(256)
void prep_kernel(const float* __restrict__ query,
                 const float* __restrict__ Wq,
                 const float* __restrict__ bq,
                 unsigned short* __restrict__ WqP,
                 float* __restrict__ hqb) {
    int blk = blockIdx.x;
    int tid = threadIdx.x;
    if (blk < 32) {
        int b = blk, col = tid;
        float acc = 2.0f * bq[col];
#pragma unroll 4
        for (int k = 0; k < QD; ++k)
            acc += query[b * QD + k] * Wq[k * HD + col];
        hqb[b * HD + col] = acc;
    } else {
        int idx = blk - 32;
        int kstep = idx >> 2, g = idx & 3;
        int col = tid;
        u16x8 v;
#pragma unroll
        for (int j = 0; j < 8; ++j)
            v[j] = f2bf(Wq[(kstep * 32 + g * 8 + j) * HD + col]);
        *reinterpret_cast<u16x8*>(WqP + kstep * 8192 + col * 32 + g * 8) = v;
    }
}

// ---------------------------------------------------------------------------
// Kernel 2 (FUSED): block = (b, 256-row chunk).
// Phase 1: 4 x {stage 64x256 key subtile -> MFMA scores -> epilogue}
//          raw scores -> global s AND LDS ss (per-head).
// Phase 2: per-wave (head) chunk-local max + exp + sum (in-place in LDS).
// Phase 3: stream value rows, accumulate p_c[h][k] = sum_n es[h][n]*v[n][k].
// Emits per-chunk partials p_part + (m_c, l_c) per head.
// ---------------------------------------------------------------------------
__global__ __launch_bounds__(256, 4)
void fused_kernel(const float* __restrict__ key,
                  const float* __restrict__ value,
                  const unsigned short* __restrict__ WqP,
                  const float* __restrict__ hqb,
                  const float* __restrict__ avec,
                  float* __restrict__ s,
                  float* __restrict__ p_part,
                  float* __restrict__ pml) {
    __shared__ __align__(16) char smem[37888];
    unsigned short (*kt)[264] = reinterpret_cast<unsigned short(*)[264]>(smem);       // 33792 B
    float (*es)[256] = reinterpret_cast<float(*)[256]>(smem + 33792);                 // 4096 B
    float (*red)[4][260] = reinterpret_cast<float(*)[4][260]>(smem);                  // aliases kt (phase 3)

    int bid = blockIdx.x;
    int b = bid >> 5, ch = bid & 31;
    int n0 = ch * 256;
    int tid = threadIdx.x;
    int w = tid >> 6;            // wave == head
    int lane = tid & 63;
    int col16 = lane & 15;
    int g = lane >> 4;
    int lh = lane >> 5;
    int lc = lane & 31;

    float hq_[4], av[4];
#pragma unroll
    for (int ct = 0; ct < 4; ++ct) {
        hq_[ct] = hqb[b * HD + w * 64 + ct * 16 + col16];
        av[ct] = avec[ct * 16 + col16];
    }

    // ---------------- Phase 1: scores for 4 subtiles of 64 rows ----------------
    for (int sub = 0; sub < 4; ++sub) {
        int r0 = n0 + sub * 64;
        const float* kb = key + ((size_t)(b * N_NODES + r0 + w * 16 + lh)) * QD + lc * 8;
#pragma unroll
        for (int st = 0; st < 8; ++st) {
            float4 f0 = *reinterpret_cast<const float4*>(kb + (size_t)(st * 2) * QD);
            float4 f1 = *reinterpret_cast<const float4*>(kb + (size_t)(st * 2) * QD + 4);
            u16x8 cv;
            cv[0] = f2bf(f0.x); cv[1] = f2bf(f0.y); cv[2] = f2bf(f0.z); cv[3] = f2bf(f0.w);
            cv[4] = f2bf(f1.x); cv[5] = f2bf(f1.y); cv[6] = f2bf(f1.z); cv[7] = f2bf(f1.w);
            *reinterpret_cast<u16x8*>(&kt[w * 16 + st * 2 + lh][lc * 8]) = cv;
        }
        __syncthreads();

        f32x4 acc[4][4];
#pragma unroll
        for (int i = 0; i < 4; ++i)
#pragma unroll
            for (int j = 0; j < 4; ++j)
                acc[i][j] = (f32x4){0.f, 0.f, 0.f, 0.f};

#pragma unroll
        for (int ks = 0; ks < 8; ++ks) {
            bf16x8 afr[4], bfr[4];
#pragma unroll
            for (int rt = 0; rt < 4; ++rt)
                afr[rt] = *reinterpret_cast<const bf16x8*>(&kt[rt * 16 + col16][ks * 32 + g * 8]);
            const unsigned short* wp = WqP + ks * 8192 + w * 2048 + g * 8;
#pragma unroll
            for (int ct = 0; ct < 4; ++ct)
                bfr[ct] = *reinterpret_cast<const bf16x8*>(wp + (ct * 16 + col16) * 32);
#pragma unroll
            for (int rt = 0; rt < 4; ++rt)
#pragma unroll
                for (int ct = 0; ct < 4; ++ct)
                    acc[rt][ct] = __builtin_amdgcn_mfma_f32_16x16x32_bf16(
                        afr[rt], bfr[ct], acc[rt][ct], 0, 0, 0);
        }

        // epilogue: leaky_relu + dot(a) + 16-lane reduce -> raw scores
#pragma unroll
        for (int rt = 0; rt < 4; ++rt) {
            float part[4] = {0.f, 0.f, 0.f, 0.f};
#pragma unroll
            for (int ct = 0; ct < 4; ++ct) {
#pragma unroll
                for (int r = 0; r < 4; ++r) {
                    float pre = acc[rt][ct][r] + hq_[ct];
                    float t = pre > 0.f ? pre : NEG_SLOPE * pre;
                    part[r] += av[ct] * t;
                }
            }
#pragma unroll
            for (int off = 1; off < 16; off <<= 1)
#pragma unroll
                for (int r = 0; r < 4; ++r)
                    part[r] += __shfl_xor(part[r], off, 64);
            if (col16 == 0) {
                int rloc = sub * 64 + rt * 16 + g * 4;
                float* sp = s + ((size_t)(b * NUM_HEADS + w)) * N_NODES + n0 + rloc;
#pragma unroll
                for (int r = 0; r < 4; ++r) {
                    sp[r] = part[r];
                    es[w][rloc + r] = part[r];
                }
            }
        }
        __syncthreads();   // protect kt before next sub restage (and red alias)
    }

    // ---------------- Phase 2: chunk-local softmax partials (wave w = head w) --
    float4 sv = *reinterpret_cast<const float4*>(&es[w][lane * 4]);
    float mx = fmaxf(fmaxf(sv.x, sv.y), fmaxf(sv.z, sv.w));
#pragma unroll
    for (int off = 1; off < 64; off <<= 1) mx = fmaxf(mx, __shfl_xor(mx, off, 64));
    float e0 = __expf(sv.x - mx), e1 = __expf(sv.y - mx);
    float e2v = __expf(sv.z - mx), e3 = __expf(sv.w - mx);
    float lsum = e0 + e1 + e2v + e3;
#pragma unroll
    for (int off = 1; off < 64; off <<= 1) lsum += __shfl_xor(lsum, off, 64);
    float4 ev = {e0, e1, e2v, e3};
    *reinterpret_cast<float4*>(&es[w][lane * 4]) = ev;
    if (lane == 0) {
        pml[bid * 8 + w] = mx;
        pml[bid * 8 + 4 + w] = lsum;
    }
    __syncthreads();

    // ---------------- Phase 3: value streaming (rows n == w mod 4) -------------
    float4 a0 = {0.f, 0.f, 0.f, 0.f}, a1 = a0, a2 = a0, a3 = a0;
    const float* vb = value + ((size_t)(b * N_NODES + n0)) * VD + lane * 4;
#pragma unroll 4
    for (int n = w; n < 256; n += 4) {
        float4 v = *reinterpret_cast<const float4*>(vb + (size_t)n * VD);
        float q0 = es[0][n], q1 = es[1][n], q2 = es[2][n], q3 = es[3][n];
        a0.x += q0 * v.x; a0.y += q0 * v.y; a0.z += q0 * v.z; a0.w += q0 * v.w;
        a1.x += q1 * v.x; a1.y += q1 * v.y; a1.z += q1 * v.z; a1.w += q1 * v.w;
        a2.x += q2 * v.x; a2.y += q2 * v.y; a2.z += q2 * v.z; a2.w += q2 * v.w;
        a3.x += q3 * v.x; a3.y += q3 * v.y; a3.z += q3 * v.z; a3.w += q3 * v.w;
    }
    *reinterpret_cast<float4*>(&red[w][0][lane * 4]) = a0;
    *reinterpret_cast<float4*>(&red[w][1][lane * 4]) = a1;
    *reinterpret_cast<float4*>(&red[w][2][lane * 4]) = a2;
    *reinterpret_cast<float4*>(&red[w][3][lane * 4]) = a3;
    __syncthreads();

    float* pp = p_part + (size_t)bid * 1024;
#pragma unroll
    for (int h = 0; h < 4; ++h)
        pp[h * 256 + tid] = red[0][h][tid] + red[1][h][tid] + red[2][h][tid] + red[3][h][tid];
}

// ---------------------------------------------------------------------------
// Kernel 3: combine chunks per (b,h): global max/sum rescale, p@Wv+bias+relu.
// Also emits (M, 1/L) per (b,h) for the e-pass.
// ---------------------------------------------------------------------------
__global__ __launch_bounds__(64)
void final_kernel(const float* __restrict__ p_part,
                  const float* __restrict__ pml,
                  const float* __restrict__ Wv,
                  const float* __restrict__ bv,
                  float* __restrict__ hout,
                  float* __restrict__ sc) {
    int bh = blockIdx.x;
    int b = bh >> 2, h = bh & 3;
    int d = threadIdx.x;

    float M = -1e30f;
#pragma unroll 8
    for (int c = 0; c < 32; ++c)
        M = fmaxf(M, pml[(b * 32 + c) * 8 + h]);
    float wf[32];
    float L = 0.f;
#pragma unroll 8
    for (int c = 0; c < 32; ++c) {
        wf[c] = __expf(pml[(b * 32 + c) * 8 + h] - M);
        L += pml[(b * 32 + c) * 8 + 4 + h] * wf[c];
    }
    float invL = 1.0f / L;

    __shared__ float ps[256];
#pragma unroll
    for (int j = 0; j < 4; ++j) {
        int k = j * 64 + d;
        float sv = 0.f;
#pragma unroll 8
        for (int c = 0; c < 32; ++c)
            sv += wf[c] * p_part[((size_t)(b * 32 + c)) * 1024 + h * 256 + k];
        ps[k] = sv * invL;
    }
    if (d == 0) {
        sc[bh * 2] = M;
        sc[bh * 2 + 1] = invL;
    }
    __syncthreads();

    float acc = bv[h * 64 + d];
#pragma unroll 4
    for (int k = 0; k < 256; ++k)
        acc += ps[k] * Wv[k * HD + h * 64 + d];
    hout[b * HD + h * 64 + d] = fmaxf(acc, 0.f);
}

// ---------------------------------------------------------------------------
// Kernel 4: e-pass. e_out[b,n,h] = exp(s[b,h,n]-M)*invL. float4 write per n.
// ---------------------------------------------------------------------------
__global__ __launch_bounds__(256)
void epass_kernel(const float* __restrict__ s,
                  const float* __restrict__ sc,
                  float* __restrict__ e_out) {
    int bid = blockIdx.x;
    int b = bid >> 5, t = bid & 31;
    int n = t * 256 + threadIdx.x;
    float4 ev;
#pragma unroll
    for (int h = 0; h < 4; ++h) {
        float M = sc[(b * 4 + h) * 2];
        float invL = sc[(b * 4 + h) * 2 + 1];
        float sv = s[((size_t)(b * 4 + h)) * N_NODES + n];
        (&ev.x)[h] = __expf(sv - M) * invL;
    }
    *reinterpret_cast<float4*>(e_out + ((size_t)(b * N_NODES + n)) * 4) = ev;
}

extern "C" void kernel_launch(void* const* d_in, const int* in_sizes, int n_in,
                              void* d_out, int out_size, void* d_ws, size_t ws_size,
                              hipStream_t stream) {
    const float* query = (const float*)d_in[0];
    const float* key   = (const float*)d_in[1];
    const float* value = (const float*)d_in[2];
    const float* Wq    = (const float*)d_in[3];
    const float* bq    = (const float*)d_in[4];
    const float* Wv    = (const float*)d_in[5];
    const float* bv    = (const float*)d_in[6];
    const float* avec  = (const float*)d_in[7];
    float* out = (float*)d_out;

    char* ws = (char*)d_ws;
    unsigned short* WqP = (unsigned short*)ws;               // 131072 B
    float* hqb    = (float*)(ws + 131072);                   // 32 KB
    float* s      = (float*)(ws + 163840);                   // 4 MB
    float* p_part = (float*)(ws + 4358144);                  // 4 MB
    float* pml    = (float*)(ws + 8552448);                  // 32 KB
    float* sc     = (float*)(ws + 8585216);                  // 1 KB

    prep_kernel<<<64, 256, 0, stream>>>(query, Wq, bq, WqP, hqb);
    fused_kernel<<<B_SZ * 32, 256, 0, stream>>>(key, value, WqP, hqb, avec, s, p_part, pml);
    final_kernel<<<B_SZ * NUM_HEADS, 64, 0, stream>>>(p_part, pml, Wv, bv, out, sc);
    epass_kernel<<<B_SZ * 32, 256, 0, stream>>>(s, sc, out + B_SZ * HD);
}

// Round 4
// 202.779 us; speedup vs baseline: 1.3196x; 1.3196x over previous
//
#include <hip/hip_runtime.h>
#include <hip/hip_bf16.h>

#define NUM_HEADS 4
#define HEAD_DIM 64
#define HD 256
#define QD 256
#define VD 256
#define B_SZ 32
#define N_NODES 8192
#define NEG_SLOPE 0.2f

typedef short bf16x8 __attribute__((ext_vector_type(8)));
typedef unsigned short u16x8 __attribute__((ext_vector_type(8)));
typedef float f32x4 __attribute__((ext_vector_type(4)));

static __device__ __forceinline__ unsigned short f2bf(float f) {
    __hip_bfloat16 h = __float2bfloat16(f);
    return *reinterpret_cast<unsigned short*>(&h);
}

// ---------------------------------------------------------------------------
// Kernel 1: prep
//  blocks 0..31 : hqb[b][col] = query[b]@Wq[:,col] + 2*bq[col]
//  blocks 32..63: pack Wq -> bf16 fragment order
// ---------------------------------------------------------------------------
__global__ __launch_bounds__(256)
void prep_kernel(const float* __restrict__ query,
                 const float* __restrict__ Wq,
                 const float* __restrict__ bq,
                 unsigned short* __restrict__ WqP,
                 float* __restrict__ hqb) {
    int blk = blockIdx.x;
    int tid = threadIdx.x;
    if (blk < 32) {
        int b = blk, col = tid;
        float acc = 2.0f * bq[col];
#pragma unroll 4
        for (int k = 0; k < QD; ++k)
            acc += query[b * QD + k] * Wq[k * HD + col];
        hqb[b * HD + col] = acc;
    } else {
        int idx = blk - 32;
        int kstep = idx >> 2, g = idx & 3;
        int col = tid;
        u16x8 v;
#pragma unroll
        for (int j = 0; j < 8; ++j)
            v[j] = f2bf(Wq[(kstep * 32 + g * 8 + j) * HD + col]);
        *reinterpret_cast<u16x8*>(WqP + kstep * 8192 + col * 32 + g * 8) = v;
    }
}

// ---------------------------------------------------------------------------
// Kernel 2: score. Block = 32 key rows of one b. Grid 8192 (>> resident
// capacity -> continuous block turnover = phase drift across the CU).
// One barrier per block. Wave w = head w, C-tile 32x64 (2x4 frags).
// ---------------------------------------------------------------------------
__global__ __launch_bounds__(256)
void score_kernel(const float* __restrict__ key,
                  const unsigned short* __restrict__ WqP,
                  const float* __restrict__ hqb,
                  const float* __restrict__ avec,
                  float* __restrict__ s) {
    __shared__ __align__(16) unsigned short kt[32][264];   // 16.5 KB

    int bid = blockIdx.x;
    int b = bid >> 8;
    int n0 = (bid & 255) * 32;
    int tid = threadIdx.x;
    int w = tid >> 6, lane = tid & 63;
    int col16 = lane & 15, g = lane >> 4;

    // ---- stage 32x256 key tile: thread t -> row t/8, 32 contiguous floats
    {
        int row = tid >> 3, c0 = (tid & 7) * 32;
        const float* kb = key + ((size_t)(b * N_NODES + n0 + row)) * QD + c0;
        float4 f[8];
#pragma unroll
        for (int i = 0; i < 8; ++i)
            f[i] = *reinterpret_cast<const float4*>(kb + i * 4);
#pragma unroll
        for (int i2 = 0; i2 < 4; ++i2) {
            u16x8 cv;
            cv[0] = f2bf(f[i2 * 2].x); cv[1] = f2bf(f[i2 * 2].y);
            cv[2] = f2bf(f[i2 * 2].z); cv[3] = f2bf(f[i2 * 2].w);
            cv[4] = f2bf(f[i2 * 2 + 1].x); cv[5] = f2bf(f[i2 * 2 + 1].y);
            cv[6] = f2bf(f[i2 * 2 + 1].z); cv[7] = f2bf(f[i2 * 2 + 1].w);
            *reinterpret_cast<u16x8*>(&kt[row][c0 + i2 * 8]) = cv;
        }
    }
    __syncthreads();

    float hq_[4], av[4];
#pragma unroll
    for (int ct = 0; ct < 4; ++ct) {
        hq_[ct] = hqb[b * HD + w * 64 + ct * 16 + col16];
        av[ct] = avec[ct * 16 + col16];
    }

    f32x4 acc[2][4];
#pragma unroll
    for (int i = 0; i < 2; ++i)
#pragma unroll
        for (int j = 0; j < 4; ++j)
            acc[i][j] = (f32x4){0.f, 0.f, 0.f, 0.f};

#pragma unroll
    for (int ks = 0; ks < 8; ++ks) {
        bf16x8 afr[2], bfr[4];
        const unsigned short* wp = WqP + ks * 8192 + w * 2048 + g * 8;
#pragma unroll
        for (int ct = 0; ct < 4; ++ct)
            bfr[ct] = *reinterpret_cast<const bf16x8*>(wp + (ct * 16 + col16) * 32);
#pragma unroll
        for (int rt = 0; rt < 2; ++rt)
            afr[rt] = *reinterpret_cast<const bf16x8*>(&kt[rt * 16 + col16][ks * 32 + g * 8]);
#pragma unroll
        for (int rt = 0; rt < 2; ++rt)
#pragma unroll
            for (int ct = 0; ct < 4; ++ct)
                acc[rt][ct] = __builtin_amdgcn_mfma_f32_16x16x32_bf16(
                    afr[rt], bfr[ct], acc[rt][ct], 0, 0, 0);
    }

    // epilogue: leaky_relu + dot(a) + 16-lane reduce -> raw scores
#pragma unroll
    for (int rt = 0; rt < 2; ++rt) {
        float part[4] = {0.f, 0.f, 0.f, 0.f};
#pragma unroll
        for (int ct = 0; ct < 4; ++ct) {
#pragma unroll
            for (int r = 0; r < 4; ++r) {
                float pre = acc[rt][ct][r] + hq_[ct];
                float t = pre > 0.f ? pre : NEG_SLOPE * pre;
                part[r] += av[ct] * t;
            }
        }
#pragma unroll
        for (int off = 1; off < 16; off <<= 1)
#pragma unroll
            for (int r = 0; r < 4; ++r)
                part[r] += __shfl_xor(part[r], off, 64);
        if (col16 == 0) {
            float* sp = s + ((size_t)(b * NUM_HEADS + w)) * N_NODES + n0 + rt * 16 + g * 4;
#pragma unroll
            for (int r = 0; r < 4; ++r) sp[r] = part[r];
        }
    }
}

// ---------------------------------------------------------------------------
// Kernel 3: softmax over n per (b,h) -> normalized e2[b][h][n] (coalesced).
// ---------------------------------------------------------------------------
__global__ __launch_bounds__(256)
void softmax_kernel(const float* __restrict__ s,
                    float* __restrict__ e2) {
    int bh = blockIdx.x;
    int tid = threadIdx.x;
    const float* sp = s + (size_t)bh * N_NODES;

    float v[32];
#pragma unroll
    for (int c = 0; c < 8; ++c) {
        float4 f = *reinterpret_cast<const float4*>(sp + c * 1024 + tid * 4);
        v[c * 4 + 0] = f.x; v[c * 4 + 1] = f.y; v[c * 4 + 2] = f.z; v[c * 4 + 3] = f.w;
    }
    float mx = -1e30f;
#pragma unroll
    for (int i = 0; i < 32; ++i) mx = fmaxf(mx, v[i]);
#pragma unroll
    for (int off = 1; off < 64; off <<= 1) mx = fmaxf(mx, __shfl_xor(mx, off, 64));

    __shared__ float redmx[4];
    __shared__ float redsum[4];
    int wv = tid >> 6, lane = tid & 63;
    if (lane == 0) redmx[wv] = mx;
    __syncthreads();
    mx = fmaxf(fmaxf(redmx[0], redmx[1]), fmaxf(redmx[2], redmx[3]));

    float sum = 0.f;
#pragma unroll
    for (int i = 0; i < 32; ++i) { v[i] = __expf(v[i] - mx); sum += v[i]; }
#pragma unroll
    for (int off = 1; off < 64; off <<= 1) sum += __shfl_xor(sum, off, 64);
    if (lane == 0) redsum[wv] = sum;
    __syncthreads();
    sum = redsum[0] + redsum[1] + redsum[2] + redsum[3];
    float inv = 1.0f / sum;

#pragma unroll
    for (int c = 0; c < 8; ++c) {
        int n = c * 1024 + tid * 4;
        float4 ev;
        ev.x = v[c * 4 + 0] * inv; ev.y = v[c * 4 + 1] * inv;
        ev.z = v[c * 4 + 2] * inv; ev.w = v[c * 4 + 3] * inv;
        *reinterpret_cast<float4*>(e2 + (size_t)bh * N_NODES + n) = ev;
    }
}

// ---------------------------------------------------------------------------
// Kernel 4: transpose e2[b][h][n] -> e_out[b][n][h] (required output; also
// pv input: one uniform float4 per row). Coalesced both sides.
// ---------------------------------------------------------------------------
__global__ __launch_bounds__(256)
void transpose_kernel(const float* __restrict__ e2,
                      float* __restrict__ e_out) {
    int bid = blockIdx.x;
    int b = bid >> 3, ch = bid & 7;
    int n = ch * 1024 + threadIdx.x * 4;
    f32x4 r[4];
#pragma unroll
    for (int h = 0; h < 4; ++h)
        r[h] = *reinterpret_cast<const f32x4*>(e2 + ((size_t)(b * 4 + h)) * N_NODES + n);
    float* eo = e_out + ((size_t)(b * N_NODES + n)) * 4;
#pragma unroll
    for (int j = 0; j < 4; ++j) {
        f32x4 o = {r[0][j], r[1][j], r[2][j], r[3][j]};
        *reinterpret_cast<f32x4*>(eo + j * 4) = o;
    }
}

// ---------------------------------------------------------------------------
// Kernel 5: pv. Block = (b, 128-row chunk); wave w streams rows [w*32,w*32+32)
// independently (no barriers in the stream). e via wave-uniform float4 from
// e_out. End-of-block LDS reduce -> p_part[bid][h][k].
// ---------------------------------------------------------------------------
__global__ __launch_bounds__(256)
void pv_kernel(const float* __restrict__ value,
               const float* __restrict__ e_out,
               float* __restrict__ p_part) {
    int bid = blockIdx.x;
    int b = bid >> 6, ch = bid & 63;
    int nw = ch * 128 + (threadIdx.x >> 6) * 32;
    int tid = threadIdx.x;
    int w = tid >> 6, lane = tid & 63;

    const float* vb = value + ((size_t)(b * N_NODES + nw)) * VD + lane * 4;
    const float* eb = e_out + ((size_t)(b * N_NODES + nw)) * 4;

    f32x4 a0 = {0.f, 0.f, 0.f, 0.f}, a1 = a0, a2 = a0, a3 = a0;
#pragma unroll 8
    for (int n = 0; n < 32; ++n) {
        f32x4 v = *reinterpret_cast<const f32x4*>(vb + (size_t)n * VD);
        f32x4 e = *reinterpret_cast<const f32x4*>(eb + n * 4);
        a0 += e[0] * v;
        a1 += e[1] * v;
        a2 += e[2] * v;
        a3 += e[3] * v;
    }

    __shared__ float red[4][4][260];
    *reinterpret_cast<f32x4*>(&red[w][0][lane * 4]) = a0;
    *reinterpret_cast<f32x4*>(&red[w][1][lane * 4]) = a1;
    *reinterpret_cast<f32x4*>(&red[w][2][lane * 4]) = a2;
    *reinterpret_cast<f32x4*>(&red[w][3][lane * 4]) = a3;
    __syncthreads();

    float* pp = p_part + (size_t)bid * 1024;
#pragma unroll
    for (int h = 0; h < 4; ++h)
        pp[h * 256 + tid] = red[0][h][tid] + red[1][h][tid] + red[2][h][tid] + red[3][h][tid];
}

// ---------------------------------------------------------------------------
// Kernel 6: final. Per (b,h): reduce 64 chunk-partials, p@Wv + bias + relu.
// ---------------------------------------------------------------------------
__global__ __launch_bounds__(256)
void final_kernel(const float* __restrict__ p_part,
                  const float* __restrict__ Wv,
                  const float* __restrict__ bv,
                  float* __restrict__ hout) {
    int bh = blockIdx.x;
    int b = bh >> 2, h = bh & 3;
    int tid = threadIdx.x;

    float sv = 0.f;
    const float* pp = p_part + (size_t)b * 64 * 1024 + h * 256 + tid;
#pragma unroll 8
    for (int c = 0; c < 64; ++c) sv += pp[(size_t)c * 1024];
    __shared__ float ps[256];
    ps[tid] = sv;
    __syncthreads();

    int d = tid & 63, kr = tid >> 6;
    float acc = 0.f;
#pragma unroll 8
    for (int k = kr * 64; k < kr * 64 + 64; ++k)
        acc += ps[k] * Wv[k * HD + h * 64 + d];
    __shared__ float rs[4][64];
    rs[kr][d] = acc;
    __syncthreads();
    if (tid < 64) {
        float o = bv[h * 64 + tid] + rs[0][tid] + rs[1][tid] + rs[2][tid] + rs[3][tid];
        hout[b * HD + h * 64 + tid] = fmaxf(o, 0.f);
    }
}

extern "C" void kernel_launch(void* const* d_in, const int* in_sizes, int n_in,
                              void* d_out, int out_size, void* d_ws, size_t ws_size,
                              hipStream_t stream) {
    const float* query = (const float*)d_in[0];
    const float* key   = (const float*)d_in[1];
    const float* value = (const float*)d_in[2];
    const float* Wq    = (const float*)d_in[3];
    const float* bq    = (const float*)d_in[4];
    const float* Wv    = (const float*)d_in[5];
    const float* bv    = (const float*)d_in[6];
    const float* avec  = (const float*)d_in[7];
    float* out = (float*)d_out;
    float* e_out = out + B_SZ * HD;

    char* ws = (char*)d_ws;
    unsigned short* WqP = (unsigned short*)ws;               // 128 KB
    float* hqb    = (float*)(ws + 131072);                   // 32 KB
    float* s      = (float*)(ws + 163840);                   // 4 MB
    float* e2     = (float*)(ws + 163840 + 4194304);         // 4 MB
    float* p_part = (float*)(ws + 163840 + 8388608);         // 8 MB

    prep_kernel<<<64, 256, 0, stream>>>(query, Wq, bq, WqP, hqb);
    score_kernel<<<B_SZ * (N_NODES / 32), 256, 0, stream>>>(key, WqP, hqb, avec, s);
    softmax_kernel<<<B_SZ * NUM_HEADS, 256, 0, stream>>>(s, e2);
    transpose_kernel<<<B_SZ * 8, 256, 0, stream>>>(e2, e_out);
    pv_kernel<<<B_SZ * 64, 256, 0, stream>>>(value, e_out, p_part);
    final_kernel<<<B_SZ * NUM_HEADS, 256, 0, stream>>>(p_part, Wv, bv, out);
}

// Round 5
// 184.757 us; speedup vs baseline: 1.4483x; 1.0975x over previous
//
#include <hip/hip_runtime.h>
#include <hip/hip_bf16.h>

#define NUM_HEADS 4
#define HD 256
#define QD 256
#define VD 256
#define B_SZ 32
#define N_NODES 8192
#define NEG_SLOPE 0.2f

typedef short bf16x8 __attribute__((ext_vector_type(8)));
typedef float f32x4 __attribute__((ext_vector_type(4)));

static __device__ __forceinline__ unsigned short f2bf(float f) {
    __hip_bfloat16 h = __float2bfloat16(f);
    return *reinterpret_cast<unsigned short*>(&h);
}

// ---------------------------------------------------------------------------
// Kernel 1: prep
//  blocks 0..31 : hqb[b][col] = query[b]@Wq[:,col] + 2*bq[col]  (unroll 16)
//  blocks 32..63: pack Wq -> bf16 fragment order
// ---------------------------------------------------------------------------
__global__ __launch_bounds__(256)
void prep_kernel(const float* __restrict__ query,
                 const float* __restrict__ Wq,
                 const float* __restrict__ bq,
                 unsigned short* __restrict__ WqP,
                 float* __restrict__ hqb) {
    int blk = blockIdx.x;
    int tid = threadIdx.x;
    if (blk < 32) {
        int b = blk, col = tid;
        float acc = 2.0f * bq[col];
#pragma unroll 16
        for (int k = 0; k < QD; ++k)
            acc += query[b * QD + k] * Wq[k * HD + col];
        hqb[b * HD + col] = acc;
    } else {
        int idx = blk - 32;
        int kstep = idx >> 2, g = idx & 3;
        int col = tid;
        unsigned short v[8];
#pragma unroll
        for (int j = 0; j < 8; ++j)
            v[j] = f2bf(Wq[(kstep * 32 + g * 8 + j) * HD + col]);
        *reinterpret_cast<uint4*>(WqP + kstep * 8192 + col * 32 + g * 8) =
            *reinterpret_cast<uint4*>(v);
    }
}

// ---------------------------------------------------------------------------
// Kernel 2 (FUSED flash): block = (b, 32-row chunk), grid 8192, 4 waves.
//  stage key tile (cvt_pk asm) -> barrier -> MFMA scores -> value prefetch
//  -> epilogue (raw s + LDS) -> chunk-local softmax (m,l) -> barrier
//  -> weighted value accumulate -> LDS reduce -> p_part.
// ---------------------------------------------------------------------------
__global__ __launch_bounds__(256)
void fused_kernel(const float* __restrict__ key,
                  const float* __restrict__ value,
                  const unsigned short* __restrict__ WqP,
                  const float* __restrict__ hqb,
                  const float* __restrict__ avec,
                  float* __restrict__ s,
                  float* __restrict__ p_part,
                  float* __restrict__ pml) {
    __shared__ __align__(16) char smem[17408];
    unsigned short (*kt)[264] = reinterpret_cast<unsigned short(*)[264]>(smem);  // 16896 B
    float (*es4)[4] = reinterpret_cast<float(*)[4]>(smem + 16896);               // 512 B
    float (*red)[4][260] = reinterpret_cast<float(*)[4][260]>(smem);             // alias kt

    int bid = blockIdx.x;
    int b = bid >> 8;
    int n0 = (bid & 255) * 32;
    int tid = threadIdx.x;
    int w = tid >> 6, lane = tid & 63;
    int col16 = lane & 15, g = lane >> 4;

    // ---- stage 32x256 key tile: thread t -> row t/8, 32 contiguous floats
    {
        int row = tid >> 3, c0 = (tid & 7) * 32;
        const float* kb = key + ((size_t)(b * N_NODES + n0 + row)) * QD + c0;
        float4 f[8];
#pragma unroll
        for (int i = 0; i < 8; ++i)
            f[i] = *reinterpret_cast<const float4*>(kb + i * 4);
        unsigned int u[16];
#pragma unroll
        for (int j = 0; j < 16; ++j) {
            float lo = (&f[j >> 1].x)[(j & 1) * 2];
            float hi = (&f[j >> 1].x)[(j & 1) * 2 + 1];
            asm("v_cvt_pk_bf16_f32 %0, %1, %2" : "=v"(u[j]) : "v"(lo), "v"(hi));
        }
#pragma unroll
        for (int i = 0; i < 4; ++i) {
            uint4 st = {u[i * 4], u[i * 4 + 1], u[i * 4 + 2], u[i * 4 + 3]};
            *reinterpret_cast<uint4*>(&kt[row][c0 + i * 8]) = st;
        }
    }

    float hq_[4], av[4];
#pragma unroll
    for (int ct = 0; ct < 4; ++ct) {
        hq_[ct] = hqb[b * HD + w * 64 + ct * 16 + col16];
        av[ct] = avec[ct * 16 + col16];
    }
    __syncthreads();

    f32x4 acc[2][4];
#pragma unroll
    for (int i = 0; i < 2; ++i)
#pragma unroll
        for (int j = 0; j < 4; ++j)
            acc[i][j] = (f32x4){0.f, 0.f, 0.f, 0.f};

#pragma unroll
    for (int ks = 0; ks < 8; ++ks) {
        bf16x8 afr[2], bfr[4];
        const unsigned short* wp = WqP + ks * 8192 + w * 2048 + g * 8;
#pragma unroll
        for (int ct = 0; ct < 4; ++ct)
            bfr[ct] = *reinterpret_cast<const bf16x8*>(wp + (ct * 16 + col16) * 32);
#pragma unroll
        for (int rt = 0; rt < 2; ++rt)
            afr[rt] = *reinterpret_cast<const bf16x8*>(&kt[rt * 16 + col16][ks * 32 + g * 8]);
#pragma unroll
        for (int rt = 0; rt < 2; ++rt)
#pragma unroll
            for (int ct = 0; ct < 4; ++ct)
                acc[rt][ct] = __builtin_amdgcn_mfma_f32_16x16x32_bf16(
                    afr[rt], bfr[ct], acc[rt][ct], 0, 0, 0);
    }

    // ---- prefetch this wave's 8 value rows (latency hides under epilogue)
    f32x4 vr[8];
    {
        const float* vb = value + ((size_t)(b * N_NODES + n0 + w * 8)) * VD + lane * 4;
#pragma unroll
        for (int r = 0; r < 8; ++r)
            vr[r] = *reinterpret_cast<const f32x4*>(vb + (size_t)r * VD);
    }

    // ---- epilogue: leaky_relu + dot(a) + 16-lane reduce -> raw scores
#pragma unroll
    for (int rt = 0; rt < 2; ++rt) {
        float part[4] = {0.f, 0.f, 0.f, 0.f};
#pragma unroll
        for (int ct = 0; ct < 4; ++ct) {
#pragma unroll
            for (int r = 0; r < 4; ++r) {
                float pre = acc[rt][ct][r] + hq_[ct];
                float t = fmaxf(pre, NEG_SLOPE * pre);   // leaky_relu, slope<1
                part[r] += av[ct] * t;
            }
        }
#pragma unroll
        for (int off = 1; off < 16; off <<= 1)
#pragma unroll
            for (int r = 0; r < 4; ++r)
                part[r] += __shfl_xor(part[r], off, 64);
        if (col16 == 0) {
            int rloc = rt * 16 + g * 4;
            float* sp = s + ((size_t)(b * NUM_HEADS + w)) * N_NODES + n0 + rloc;
#pragma unroll
            for (int r = 0; r < 4; ++r) {
                sp[r] = part[r];
                es4[rloc + r][w] = part[r];
            }
        }
    }

    // ---- chunk-local softmax for head w over 32 rows
    {
        float sv = es4[lane & 31][w];
        float m = sv;
#pragma unroll
        for (int off = 1; off < 32; off <<= 1) m = fmaxf(m, __shfl_xor(m, off, 64));
        float ep = __expf(sv - m);
        float ls = ep;
#pragma unroll
        for (int off = 1; off < 32; off <<= 1) ls += __shfl_xor(ls, off, 64);
        if (lane < 32) es4[lane][w] = ep;
        if (lane == 0) {
            pml[(size_t)bid * 8 + w] = m;
            pml[(size_t)bid * 8 + 4 + w] = ls;
        }
    }
    __syncthreads();   // es4 complete for all heads; kt reads all retired

    // ---- weighted value accumulate: wave w owns rows [w*8, w*8+8)
    f32x4 a0 = {0.f, 0.f, 0.f, 0.f}, a1 = a0, a2 = a0, a3 = a0;
#pragma unroll
    for (int r = 0; r < 8; ++r) {
        int n = w * 8 + r;
        f32x4 ev = *reinterpret_cast<const f32x4*>(&es4[n][0]);
        a0 += ev[0] * vr[r];
        a1 += ev[1] * vr[r];
        a2 += ev[2] * vr[r];
        a3 += ev[3] * vr[r];
    }
    *reinterpret_cast<f32x4*>(&red[w][0][lane * 4]) = a0;
    *reinterpret_cast<f32x4*>(&red[w][1][lane * 4]) = a1;
    *reinterpret_cast<f32x4*>(&red[w][2][lane * 4]) = a2;
    *reinterpret_cast<f32x4*>(&red[w][3][lane * 4]) = a3;
    __syncthreads();

    float* pp = p_part + (size_t)bid * 1024;
#pragma unroll
    for (int h = 0; h < 4; ++h)
        pp[h * 256 + tid] = red[0][h][tid] + red[1][h][tid] + red[2][h][tid] + red[3][h][tid];
}

// ---------------------------------------------------------------------------
// Kernel 3: final. Per (b,h): global M, L from 256 chunk (m,l); rescale and
// reduce p_part; p@Wv + bias + relu; emit (M, invL) for epass.
// ---------------------------------------------------------------------------
__global__ __launch_bounds__(256)
void final_kernel(const float* __restrict__ p_part,
                  const float* __restrict__ pml,
                  const float* __restrict__ Wv,
                  const float* __restrict__ bv,
                  float* __restrict__ hout,
                  float* __restrict__ sc) {
    int bh = blockIdx.x;
    int b = bh >> 2, h = bh & 3;
    int tid = threadIdx.x;
    int wv = tid >> 6, lane = tid & 63;

    float mc = pml[((size_t)(b * 256 + tid)) * 8 + h];
    float lc = pml[((size_t)(b * 256 + tid)) * 8 + 4 + h];

    __shared__ float r4a[4], r4b[4];
    float M = mc;
#pragma unroll
    for (int off = 1; off < 64; off <<= 1) M = fmaxf(M, __shfl_xor(M, off, 64));
    if (lane == 0) r4a[wv] = M;
    __syncthreads();
    M = fmaxf(fmaxf(r4a[0], r4a[1]), fmaxf(r4a[2], r4a[3]));

    __shared__ float wfs[256];
    float wf = __expf(mc - M);
    wfs[tid] = wf;
    float Lp = wf * lc;
#pragma unroll
    for (int off = 1; off < 64; off <<= 1) Lp += __shfl_xor(Lp, off, 64);
    if (lane == 0) r4b[wv] = Lp;
    __syncthreads();
    float L = r4b[0] + r4b[1] + r4b[2] + r4b[3];
    float invL = 1.0f / L;
    if (tid == 0) {
        sc[bh * 2] = M;
        sc[bh * 2 + 1] = invL;
    }

    float acc = 0.f;
    const float* pp = p_part + ((size_t)(b * 256)) * 1024 + h * 256 + tid;
#pragma unroll 8
    for (int c = 0; c < 256; ++c)
        acc += wfs[c] * pp[(size_t)c * 1024];
    __shared__ float ps[256];
    ps[tid] = acc * invL;
    __syncthreads();

    int d = tid & 63, kr = tid >> 6;
    float a2 = 0.f;
#pragma unroll 8
    for (int k = kr * 64; k < kr * 64 + 64; ++k)
        a2 += ps[k] * Wv[k * HD + h * 64 + d];
    __shared__ float rs[4][64];
    rs[kr][d] = a2;
    __syncthreads();
    if (tid < 64) {
        float o = bv[h * 64 + tid] + rs[0][tid] + rs[1][tid] + rs[2][tid] + rs[3][tid];
        hout[b * HD + h * 64 + tid] = fmaxf(o, 0.f);
    }
}

// ---------------------------------------------------------------------------
// Kernel 4: e-pass. e_out[b,n,h] = exp(s[b,h,n]-M)*invL (s is L2/L3-hot).
// ---------------------------------------------------------------------------
__global__ __launch_bounds__(256)
void epass_kernel(const float* __restrict__ s,
                  const float* __restrict__ sc,
                  float* __restrict__ e_out) {
    int bid = blockIdx.x;
    int b = bid >> 5, t = bid & 31;
    int n = t * 256 + threadIdx.x;
    float4 ev;
#pragma unroll
    for (int h = 0; h < 4; ++h) {
        float M = sc[(b * 4 + h) * 2];
        float invL = sc[(b * 4 + h) * 2 + 1];
        float sv = s[((size_t)(b * 4 + h)) * N_NODES + n];
        (&ev.x)[h] = __expf(sv - M) * invL;
    }
    *reinterpret_cast<float4*>(e_out + ((size_t)(b * N_NODES + n)) * 4) = ev;
}

extern "C" void kernel_launch(void* const* d_in, const int* in_sizes, int n_in,
                              void* d_out, int out_size, void* d_ws, size_t ws_size,
                              hipStream_t stream) {
    const float* query = (const float*)d_in[0];
    const float* key   = (const float*)d_in[1];
    const float* value = (const float*)d_in[2];
    const float* Wq    = (const float*)d_in[3];
    const float* bq    = (const float*)d_in[4];
    const float* Wv    = (const float*)d_in[5];
    const float* bv    = (const float*)d_in[6];
    const float* avec  = (const float*)d_in[7];
    float* out = (float*)d_out;
    float* e_out = out + B_SZ * HD;

    char* ws = (char*)d_ws;
    unsigned short* WqP = (unsigned short*)ws;               // 128 KB
    float* hqb    = (float*)(ws + 131072);                   // 32 KB
    float* s      = (float*)(ws + 163840);                   // 4 MB
    float* pml    = (float*)(ws + 163840 + 4194304);         // 256 KB
    float* sc     = (float*)(ws + 163840 + 4194304 + 262144);// 1 KB
    float* p_part = (float*)(ws + 163840 + 4194304 + 262144 + 4096); // 32 MB

    prep_kernel<<<64, 256, 0, stream>>>(query, Wq, bq, WqP, hqb);
    fused_kernel<<<B_SZ * 256, 256, 0, stream>>>(key, value, WqP, hqb, avec, s, p_part, pml);
    final_kernel<<<B_SZ * NUM_HEADS, 256, 0, stream>>>(p_part, pml, Wv, bv, out, sc);
    epass_kernel<<<B_SZ * 32, 256, 0, stream>>>(s, sc, out + B_SZ * HD);
}